// Round 3
// baseline (641.962 us; speedup 1.0000x reference)
//
#include <hip/hip_runtime.h>
#include <math.h>

// Problem constants
#define NTOK 4096      // B*T
#define DIM  1024
#define NE   8
#define FF   4096

// d_out layout (floats): output | gate_logits | topk_idx | expert_counts
#define OUT_LOGITS 4194304
#define OUT_IDX    4227072
#define OUT_CNT    4235264

typedef unsigned short u16;
typedef __bf16 bf16x8 __attribute__((ext_vector_type(8)));
typedef float  f32x4  __attribute__((ext_vector_type(4)));
typedef u16    u16x8  __attribute__((ext_vector_type(8)));

__device__ __forceinline__ u16 f2bf(float f) {
  union { float f; unsigned u; } v; v.f = f;
  unsigned r = v.u + 0x7fffu + ((v.u >> 16) & 1u);
  return (u16)(r >> 16);
}

__device__ __forceinline__ float gelu_f(float v) {
  // tanh-approx gelu; |err| vs exact < ~3e-3 absolute, well under 2% threshold
  float u = v * (0.7978845608f + 0.0356774081f * v * v);
  float e = __expf(2.f * u);
  float t = 1.f - 2.f / (e + 1.f);
  return 0.5f * v * (1.f + t);
}

__device__ __forceinline__ void gload_lds16(const u16* g, u16* l) {
  __builtin_amdgcn_global_load_lds(
      (const __attribute__((address_space(1))) void*)(g),
      (__attribute__((address_space(3))) void*)(l), 16, 0, 0);
}

template <int N>
__device__ __forceinline__ void wait_vm() {
  if constexpr (N == 0)      asm volatile("s_waitcnt vmcnt(0)" ::: "memory");
  else if constexpr (N == 1) asm volatile("s_waitcnt vmcnt(1)" ::: "memory");
  else if constexpr (N == 2) asm volatile("s_waitcnt vmcnt(2)" ::: "memory");
  else if constexpr (N == 3) asm volatile("s_waitcnt vmcnt(3)" ::: "memory");
  else if constexpr (N == 4) asm volatile("s_waitcnt vmcnt(4)" ::: "memory");
  else if constexpr (N == 6) asm volatile("s_waitcnt vmcnt(6)" ::: "memory");
  else if constexpr (N == 8) asm volatile("s_waitcnt vmcnt(8)" ::: "memory");
}

// ---------------- merged transpose+convert for BOTH weight tensors ----------------
// in[R][C] f32 -> out[C][R] bf16, 64x64 tiles. XOR-swizzled f32 LDS tile; 128B
// contiguous output segments per 8 threads. (See round-1 notes.)
__global__ __launch_bounds__(256) void transpose_cvt2_kernel(
    const float* __restrict__ w1, u16* __restrict__ w1t,
    const float* __restrict__ w2, u16* __restrict__ w2t) {
  __shared__ float tile[4096];
  int id = blockIdx.x;
  const float* in; u16* out; int R, C, xt, yt, z;
  if (id < 8192) {            // w1: [DIM][FF] -> [FF][DIM], 8 experts
    in = w1; out = w1t; R = DIM; C = FF;
    xt = id & 63; yt = (id >> 6) & 15; z = id >> 10;
  } else {                    // w2: [FF][DIM] -> [DIM][FF], 8 experts
    int i2 = id - 8192;
    in = w2; out = w2t; R = FF; C = DIM;
    xt = i2 & 15; yt = (i2 >> 4) & 63; z = i2 >> 10;
  }
  in  += (size_t)z * R * C;
  out += (size_t)z * R * C;
  const int c0 = xt * 64, r0 = yt * 64;
  const int t = threadIdx.x;

  {
    int cc = t & 15, rr = t >> 4;
    #pragma unroll
    for (int p = 0; p < 4; p++) {
      int r = rr + p * 16;
      float4 v = *(const float4*)(in + (size_t)(r0 + r) * C + c0 + cc * 4);
      *(float4*)&tile[r * 64 + ((cc ^ (r >> 3)) << 2)] = v;
    }
  }
  __syncthreads();
  {
    int h = t & 7, cg = t >> 3;
    #pragma unroll
    for (int p = 0; p < 2; p++) {
      int c = p * 32 + cg;
      int base = ((((c >> 2) ^ h) << 2)) + (c & 3);
      u16x8 o;
      #pragma unroll
      for (int j = 0; j < 8; j++)
        o[j] = f2bf(tile[(h * 8 + j) * 64 + base]);
      *(u16x8*)(out + (size_t)(c0 + c) * R + r0 + h * 8) = o;
    }
  }
}

// ---------------- gate: fp32 logits, top-2, softmax; NO atomics ----------------
__global__ __launch_bounds__(256) void gate_kernel(const float* __restrict__ x,
                                                   const float* __restrict__ gw,
                                                   const float* __restrict__ gb,
                                                   float* __restrict__ out,
                                                   int2* __restrict__ tk_idx,
                                                   float2* __restrict__ tk_w) {
  int wave = threadIdx.x >> 6, lane = threadIdx.x & 63;
  int token = blockIdx.x * 4 + wave;
  const float* xr = x + (size_t)token * DIM + lane * 16;
  float acc[NE];
  #pragma unroll
  for (int e = 0; e < NE; e++) acc[e] = 0.f;
  #pragma unroll
  for (int c = 0; c < 16; c += 4) {
    float4 xv = *(const float4*)(xr + c);
    const float* gwr = gw + (size_t)(lane * 16 + c) * NE;
    float xs[4] = {xv.x, xv.y, xv.z, xv.w};
    #pragma unroll
    for (int q = 0; q < 4; q++)
      #pragma unroll
      for (int e = 0; e < NE; e++)
        acc[e] += xs[q] * gwr[q * NE + e];
  }
  #pragma unroll
  for (int off = 32; off; off >>= 1)
    #pragma unroll
    for (int e = 0; e < NE; e++)
      acc[e] += __shfl_down(acc[e], off);

  if (lane == 0) {
    float lg[NE];
    #pragma unroll
    for (int e = 0; e < NE; e++) {
      lg[e] = acc[e] + gb[e];
      out[OUT_LOGITS + token * NE + e] = lg[e];
    }
    int i0 = 0; float v0 = lg[0];
    #pragma unroll
    for (int e = 1; e < NE; e++) if (lg[e] > v0) { v0 = lg[e]; i0 = e; }
    int i1 = -1; float v1 = -1e30f;
    #pragma unroll
    for (int e = 0; e < NE; e++) if (e != i0 && lg[e] > v1) { v1 = lg[e]; i1 = e; }
    float ex = expf(v1 - v0);
    float s = 1.f + ex;
    out[OUT_IDX + token * 2]     = (float)i0;
    out[OUT_IDX + token * 2 + 1] = (float)i1;
    tk_idx[token] = make_int2(i0, i1);
    tk_w[token]   = make_float2(1.f / s, ex / s);
  }
}

// ---------------- build flat routing lists: 1 block, wave e compacts expert e ----------------
__global__ __launch_bounds__(512) void build_lists_kernel(
    const int2* __restrict__ tk_idx, const float2* __restrict__ tk_w,
    int* __restrict__ counts, int* __restrict__ offsets,
    int* __restrict__ tok_list, float* __restrict__ wt_list,
    float* __restrict__ cnt_out) {
  __shared__ int s_cnt[NE];
  int e = threadIdx.x >> 6, lane = threadIdx.x & 63;
  // phase 1: count
  int cnt = 0;
  for (int base = 0; base < NTOK; base += 64) {
    int2 idx = tk_idx[base + lane];
    cnt += __popcll(__ballot(idx.x == e || idx.y == e));
  }
  if (lane == 0) s_cnt[e] = cnt;
  __syncthreads();
  int off = 0;
  for (int ee = 0; ee < e; ee++) off += s_cnt[ee];
  if (lane == 0) {
    counts[e]  = s_cnt[e];
    offsets[e] = off;
    cnt_out[e] = (float)s_cnt[e];
  }
  // phase 2: emit (deterministic, ordered by token)
  int pos = off;
  for (int base = 0; base < NTOK; base += 64) {
    int tok = base + lane;
    int2 idx = tk_idx[tok];
    float2 w = tk_w[tok];
    bool m0 = (idx.x == e), m1 = (idx.y == e);
    bool m = m0 || m1;
    unsigned long long mask = __ballot(m);
    if (m) {
      int p = pos + __popcll(mask & ((1ull << lane) - 1ull));
      tok_list[p] = tok;
      wt_list[p]  = m0 ? w.x : w.y;
    }
    pos += __popcll(mask);
  }
}

// ---------------- gather + convert: xg[slot][:] = bf16(x[tok_list[slot]][:]) ----------------
__global__ __launch_bounds__(256) void gather_x_kernel(const float* __restrict__ x,
                                                       const int* __restrict__ tok_list,
                                                       u16* __restrict__ xg) {
  int g = blockIdx.x;
  int tok = tok_list[g];
  int c = threadIdx.x * 4;
  float4 v = *(const float4*)(x + (size_t)tok * DIM + c);
  ushort4 o;
  o.x = f2bf(v.x); o.y = f2bf(v.y); o.z = f2bf(v.z); o.w = f2bf(v.w);
  *(ushort4*)(xg + (size_t)g * DIM + c) = o;
}

// ---------------- MoE GEMM v3: 4-slot ring, BK=32, counted vmcnt (T3/T4), setprio (T5) ----
// MODE 0: xg[slot][DIM] x w1t[e][FF][DIM] -> h (gelu, bf16)   BM=256 BN=256
// MODE 1: h[slot][FF]   x w2t[e][DIM][FF] -> out (atomics)    BM=128 BN=256
// Ring schedule per step kt: stage(kt+3) | ds_read+MFMA(kt) | vmcnt(2L) | barrier.
// Invariants: (a) step kt's loads landed: ensured by step kt-1's vmcnt(2L)+barrier
// (own-wave count + barrier = all waves); (b) slot reuse: stage(kt+3) writes slot
// (kt-1)&3, whose ds_reads were all register-consumed (MFMA operands) before the
// step kt-1 trailing barrier. vmcnt never drains to 0 in the main loop.
// LDS swizzle: 4 chunks/row, clog = c ^ ((row^(row>>2))&3): per-row bijective,
// rows sharing a chunk alternate bank parity -> 2-way (free, m136). Read-side XOR
// collapses to loop-invariant csw since all frag-row bases are multiples of 16.
template <int MODE, int BM, int BN>
__global__ __launch_bounds__(512, 2) void moe_gemm3_kernel(
    const u16* __restrict__ Abase, const u16* __restrict__ Bbase,
    const float* __restrict__ bias,
    const int* __restrict__ counts, const int* __restrict__ offsets,
    const int* __restrict__ tok_list, const float* __restrict__ wt_list,
    u16* __restrict__ Hout, float* __restrict__ Out) {
  constexpr int KT = (MODE == 0) ? DIM : FF;   // reduction length
  constexpr int NT = (MODE == 0) ? FF : DIM;   // output width
  constexpr int NK = KT / 32;                  // K-steps
  constexpr int LA = BM / 128;                 // A gloads / thread / step
  constexpr int LB = BN / 128;                 // B gloads / thread / step
  constexpr int L  = LA + LB;                  // loads / thread / step
  constexpr int MR = BM / 32;                  // 16-row frags per wave (2 M-waves)
  constexpr int NR = BN / 64;                  // 16-col frags per wave (4 N-waves)
  constexpr int ASLOT = BM * 32;               // u16 per A slot
  constexpr int BSLOT = BN * 32;

  extern __shared__ u16 sm[];                  // A[4][ASLOT] | B[4][BSLOT]

  const int e  = blockIdx.z;
  const int ne = counts[e];
  const int m0 = blockIdx.y * BM;
  if (m0 >= ne) return;
  const int n0   = blockIdx.x * BN;
  const int offs = offsets[e];

  const int t = threadIdx.x;
  const int wave = t >> 6, lane = t & 63;
  const int quad = lane >> 4, l16 = lane & 15;
  const int wmb = (wave & 1) * (BM / 2);
  const int wnb = (wave >> 1) * (BN / 4);

  // ---- staging pointers (global source pre-swizzled; LDS dest linear) ----
  const u16* aptr[LA];
  const u16* bptr[LB];
  #pragma unroll
  for (int p = 0; p < LA; p++) {
    int idx = p * 512 + t;
    int row = idx >> 2, c = idx & 3;
    int clog = c ^ ((row ^ (row >> 2)) & 3);
    int s = m0 + row; if (s > ne - 1) s = ne - 1;   // clamped gather (dup last row)
    aptr[p] = Abase + (size_t)(offs + s) * KT + clog * 8;
  }
  #pragma unroll
  for (int p = 0; p < LB; p++) {
    int idx = p * 512 + t;
    int row = idx >> 2, c = idx & 3;
    int clog = c ^ ((row ^ (row >> 2)) & 3);
    bptr[p] = Bbase + ((size_t)e * NT + n0 + row) * KT + clog * 8;
  }

  auto stage = [&](int slot, int kt) {
    #pragma unroll
    for (int p = 0; p < LA; p++)
      gload_lds16(aptr[p] + kt * 32, sm + slot * ASLOT + (p * 512 + t) * 8);
    #pragma unroll
    for (int p = 0; p < LB; p++)
      gload_lds16(bptr[p] + kt * 32, sm + 4 * ASLOT + slot * BSLOT + (p * 512 + t) * 8);
  };

  // ---- loop-invariant fragment read offsets (u16 units) ----
  const int csw = ((l16 ^ (l16 >> 2)) ^ quad) & 3;
  const int aoff = (wmb + l16) * 32 + csw * 8;               // + slot*ASLOT + i*512
  const int boff = 4 * ASLOT + (wnb + l16) * 32 + csw * 8;   // + slot*BSLOT + j*512

  f32x4 acc[MR][NR];
  #pragma unroll
  for (int i = 0; i < MR; i++)
    #pragma unroll
    for (int j = 0; j < NR; j++)
      acc[i][j] = (f32x4){0.f, 0.f, 0.f, 0.f};

  auto compute = [&](int slot) {
    const u16* As = sm + slot * ASLOT + aoff;
    const u16* Bs = sm + slot * BSLOT + boff;
    bf16x8 a[MR], b[NR];
    #pragma unroll
    for (int i = 0; i < MR; i++) a[i] = *(const bf16x8*)&As[i * 512];
    #pragma unroll
    for (int j = 0; j < NR; j++) b[j] = *(const bf16x8*)&Bs[j * 512];
    __builtin_amdgcn_s_setprio(1);
    #pragma unroll
    for (int i = 0; i < MR; i++)
      #pragma unroll
      for (int j = 0; j < NR; j++)
        acc[i][j] = __builtin_amdgcn_mfma_f32_16x16x32_bf16(a[i], b[j], acc[i][j], 0, 0, 0);
    __builtin_amdgcn_s_setprio(0);
  };

  // ---- prologue: 3 steps in flight, wait step 0 ----
  stage(0, 0); stage(1, 1); stage(2, 2);
  wait_vm<2 * L>();
  __builtin_amdgcn_s_barrier();
  __builtin_amdgcn_sched_barrier(0);

  // ---- main ring: stage kt+3, compute kt, counted wait (kt+1 landed), barrier ----
  for (int kt = 0; kt < NK - 3; ++kt) {
    stage((kt + 3) & 3, kt + 3);
    compute(kt & 3);
    wait_vm<2 * L>();
    __builtin_amdgcn_s_barrier();
    __builtin_amdgcn_sched_barrier(0);
  }
  // ---- drain: 3 steps left, no new stages ----
  compute((NK - 3) & 3);
  wait_vm<L>();
  __builtin_amdgcn_s_barrier();
  __builtin_amdgcn_sched_barrier(0);
  compute((NK - 2) & 3);
  wait_vm<0>();
  __builtin_amdgcn_s_barrier();
  __builtin_amdgcn_sched_barrier(0);
  compute((NK - 1) & 3);

  // ---- epilogue ----
  if (MODE == 0) {
    const float* bb = bias + (size_t)e * FF + n0 + wnb;
    float bc[NR];
    #pragma unroll
    for (int j = 0; j < NR; j++) bc[j] = bb[j * 16 + l16];
    #pragma unroll
    for (int i = 0; i < MR; i++) {
      #pragma unroll
      for (int r = 0; r < 4; r++) {
        int s = m0 + wmb + i * 16 + quad * 4 + r;
        if (s < ne) {
          u16* hr = Hout + (size_t)(offs + s) * FF + n0 + wnb;
          #pragma unroll
          for (int j = 0; j < NR; j++)
            hr[j * 16 + l16] = f2bf(gelu_f(acc[i][j][r] + bc[j]));
        }
      }
    }
  } else {
    const float* bb = bias + (size_t)e * DIM + n0 + wnb;
    float bc[NR];
    #pragma unroll
    for (int j = 0; j < NR; j++) bc[j] = bb[j * 16 + l16];
    #pragma unroll
    for (int i = 0; i < MR; i++) {
      #pragma unroll
      for (int r = 0; r < 4; r++) {
        int s = m0 + wmb + i * 16 + quad * 4 + r;
        if (s < ne) {
          int   tok = tok_list[offs + s];
          float w   = wt_list[offs + s];
          float* orow = Out + (size_t)tok * DIM + n0 + wnb;
          #pragma unroll
          for (int j = 0; j < NR; j++)
            atomicAdd(&orow[j * 16 + l16], (acc[i][j][r] + bc[j]) * w);
        }
      }
    }
  }
}

extern "C" void kernel_launch(void* const* d_in, const int* in_sizes, int n_in,
                              void* d_out, int out_size, void* d_ws, size_t ws_size,
                              hipStream_t stream) {
  const float* x   = (const float*)d_in[0];
  const float* gw  = (const float*)d_in[1];
  const float* gb  = (const float*)d_in[2];
  const float* w1  = (const float*)d_in[3];
  const float* b1  = (const float*)d_in[4];
  const float* w2  = (const float*)d_in[5];
  const float* b2  = (const float*)d_in[6];
  float* out = (float*)d_out;
  char*  ws  = (char*)d_ws;

  // ws layout
  u16* w1t = (u16*)(ws);                                    // 64 MB  [E][FF][DIM]
  u16* w2t = (u16*)(ws + 1ull * 67108864);                  // 64 MB  [E][DIM][FF]
  u16* h   = (u16*)(ws + 2ull * 67108864);                  // 64 MB  [8192][FF]
  u16* xg  = (u16*)(ws + 3ull * 67108864);                  // 16 MB  [8192][DIM]
  char* meta = ws + 3ull * 67108864 + 16777216;
  int*    counts   = (int*)(meta);
  int*    offsets  = (int*)(meta + 64);
  int*    tok_list = (int*)(meta + 128);                    // flat [8192]
  float*  wt_list  = (float*)(meta + 128 + 32768);          // flat [8192]
  int2*   tk_idx   = (int2*)(meta + 128 + 2 * 32768);       // [4096]
  float2* tk_w     = (float2*)(meta + 128 + 2 * 32768 + 32768);
  (void)in_sizes; (void)n_in; (void)out_size; (void)ws_size;

  // dynamic-LDS opt-in (>64KB); host-side, not a stream op (graph-capture safe)
  static bool attr_set = false;
  if (!attr_set) {
    hipFuncSetAttribute(reinterpret_cast<const void*>(moe_gemm3_kernel<0, 256, 256>),
                        hipFuncAttributeMaxDynamicSharedMemorySize, 131072);
    hipFuncSetAttribute(reinterpret_cast<const void*>(moe_gemm3_kernel<1, 128, 256>),
                        hipFuncAttributeMaxDynamicSharedMemorySize, 98304);
    attr_set = true;
  }

  hipMemsetAsync(out, 0, (size_t)OUT_LOGITS * 4, stream);   // zero main output (atomics accumulate)

  transpose_cvt2_kernel<<<16384, 256, 0, stream>>>(w1, w1t, w2, w2t);
  gate_kernel<<<NTOK / 4, 256, 0, stream>>>(x, gw, gb, out, tk_idx, tk_w);
  build_lists_kernel<<<1, 512, 0, stream>>>(tk_idx, tk_w, counts, offsets, tok_list, wt_list,
                                            out + OUT_CNT);
  gather_x_kernel<<<2 * NTOK, 256, 0, stream>>>(x, tok_list, xg);

  // GEMM1: M=slots(~8192 over experts), N=4096, K=1024 -> 256x256 tiles, 32 K-steps
  moe_gemm3_kernel<0, 256, 256><<<dim3(FF / 256, NTOK / 256, NE), 512, 131072, stream>>>(
      xg, w1t, b1, counts, offsets, tok_list, wt_list, h, nullptr);
  // GEMM2: M=slots, N=1024, K=4096 -> 128x256 tiles, 128 K-steps (no K-split)
  moe_gemm3_kernel<1, 128, 256><<<dim3(DIM / 256, NTOK / 128, NE), 512, 98304, stream>>>(
      h, w2t, b2, counts, offsets, tok_list, wt_list, nullptr, out);
}

// Round 4
// 606.300 us; speedup vs baseline: 1.0588x; 1.0588x over previous
//
#include <hip/hip_runtime.h>
#include <math.h>

// Problem constants
#define NTOK 4096      // B*T
#define DIM  1024
#define NE   8
#define FF   4096

// d_out layout (floats): output | gate_logits | topk_idx | expert_counts
#define OUT_LOGITS 4194304
#define OUT_IDX    4227072
#define OUT_CNT    4235264

typedef unsigned short u16;
typedef __bf16 bf16x8 __attribute__((ext_vector_type(8)));
typedef float  f32x4  __attribute__((ext_vector_type(4)));
typedef u16    u16x8  __attribute__((ext_vector_type(8)));

__device__ __forceinline__ u16 f2bf(float f) {
  union { float f; unsigned u; } v; v.f = f;
  unsigned r = v.u + 0x7fffu + ((v.u >> 16) & 1u);
  return (u16)(r >> 16);
}

__device__ __forceinline__ float gelu_f(float v) {
  // tanh-approx gelu; |err| vs exact < ~3e-3 absolute, well under 2% threshold
  float u = v * (0.7978845608f + 0.0356774081f * v * v);
  float e = __expf(2.f * u);
  float t = 1.f - 2.f / (e + 1.f);
  return 0.5f * v * (1.f + t);
}

__device__ __forceinline__ void gload_lds16(const u16* g, u16* l) {
  __builtin_amdgcn_global_load_lds(
      (const __attribute__((address_space(1))) void*)(g),
      (__attribute__((address_space(3))) void*)(l), 16, 0, 0);
}

// ---------------- transpose+convert v3: in[R][C] f32 -> out[C][R] bf16 ----------------
// 128r x 64c tiles, 32 KB LDS, 4 blocks/CU. Output written as 256B-contiguous
// segments (4 rows x 256B per wave-store). LDS swizzle: f32x4 chunk phys = cc ^ (r>>3).
//  - store side (per 16-lane row-phase): 16 distinct chunks -> min 2-way (free)
//  - read side (per wave: h=t&15 = r>>3, cg=t>>4): phys = chunkbase ^ h -> 16 distinct
//    chunk groups x 4 byte-lanes = all 32 banks, exact 2-way (free)
__global__ __launch_bounds__(256) void transpose_cvt3_kernel(
    const float* __restrict__ w1, u16* __restrict__ w1t,
    const float* __restrict__ w2, u16* __restrict__ w2t) {
  __shared__ float tile[8192];   // [128][64] f32, chunk-swizzled
  int id = blockIdx.x;
  const float* in; u16* out; int R, C, xt, yt, z;
  if (id < 4096) {               // w1: [1024][4096] -> [4096][1024]; 8 r-tiles x 64 c-tiles
    in = w1; out = w1t; R = DIM; C = FF;
    xt = id & 63; yt = (id >> 6) & 7; z = id >> 9;
  } else {                       // w2: [4096][1024] -> [1024][4096]; 32 r-tiles x 16 c-tiles
    int i2 = id - 4096;
    in = w2; out = w2t; R = FF; C = DIM;
    xt = i2 & 15; yt = (i2 >> 4) & 31; z = i2 >> 9;
  }
  in  += (size_t)z * R * C;
  out += (size_t)z * R * C;
  const int c0 = xt * 64, r0 = yt * 128;
  const int t = threadIdx.x;

  {
    int cc = t & 15, rr = t >> 4;      // 16 rows/pass, 8 passes
    #pragma unroll
    for (int p = 0; p < 8; p++) {
      int r = rr + p * 16;
      float4 v = *(const float4*)(in + (size_t)(r0 + r) * C + c0 + cc * 4);
      *(float4*)&tile[r * 64 + ((cc ^ (r >> 3)) << 2)] = v;
    }
  }
  __syncthreads();
  {
    int h = t & 15, cg = t >> 4;       // h indexes r-octet; 16 c per pass, 4 passes
    #pragma unroll
    for (int q = 0; q < 4; q++) {
      int c = q * 16 + cg;
      int phys = ((q * 4 + (cg >> 2)) ^ h) << 2;   // loop-invariant over j (r>>3 == h)
      int base = phys + (cg & 3);
      u16x8 o;
      #pragma unroll
      for (int j = 0; j < 8; j++)
        o[j] = f2bf(tile[(h * 8 + j) * 64 + base]);
      *(u16x8*)(out + (size_t)(c0 + c) * R + r0 + h * 8) = o;
    }
  }
}

// ---------------- gate: fp32 logits, top-2, softmax; NO atomics ----------------
__global__ __launch_bounds__(256) void gate_kernel(const float* __restrict__ x,
                                                   const float* __restrict__ gw,
                                                   const float* __restrict__ gb,
                                                   float* __restrict__ out,
                                                   int2* __restrict__ tk_idx,
                                                   float2* __restrict__ tk_w) {
  int wave = threadIdx.x >> 6, lane = threadIdx.x & 63;
  int token = blockIdx.x * 4 + wave;
  const float* xr = x + (size_t)token * DIM + lane * 16;
  float acc[NE];
  #pragma unroll
  for (int e = 0; e < NE; e++) acc[e] = 0.f;
  #pragma unroll
  for (int c = 0; c < 16; c += 4) {
    float4 xv = *(const float4*)(xr + c);
    const float* gwr = gw + (size_t)(lane * 16 + c) * NE;
    float xs[4] = {xv.x, xv.y, xv.z, xv.w};
    #pragma unroll
    for (int q = 0; q < 4; q++)
      #pragma unroll
      for (int e = 0; e < NE; e++)
        acc[e] += xs[q] * gwr[q * NE + e];
  }
  #pragma unroll
  for (int off = 32; off; off >>= 1)
    #pragma unroll
    for (int e = 0; e < NE; e++)
      acc[e] += __shfl_down(acc[e], off);

  if (lane == 0) {
    float lg[NE];
    #pragma unroll
    for (int e = 0; e < NE; e++) {
      lg[e] = acc[e] + gb[e];
      out[OUT_LOGITS + token * NE + e] = lg[e];
    }
    int i0 = 0; float v0 = lg[0];
    #pragma unroll
    for (int e = 1; e < NE; e++) if (lg[e] > v0) { v0 = lg[e]; i0 = e; }
    int i1 = -1; float v1 = -1e30f;
    #pragma unroll
    for (int e = 0; e < NE; e++) if (e != i0 && lg[e] > v1) { v1 = lg[e]; i1 = e; }
    float ex = expf(v1 - v0);
    float s = 1.f + ex;
    out[OUT_IDX + token * 2]     = (float)i0;
    out[OUT_IDX + token * 2 + 1] = (float)i1;
    tk_idx[token] = make_int2(i0, i1);
    tk_w[token]   = make_float2(1.f / s, ex / s);
  }
}

// ---------------- build flat routing lists v2: 8 blocks (block e handles expert e) ----
// Every block redundantly counts ALL experts over wave-striped tokens (8 iters/wave),
// so offsets need no cross-block communication. Emit is token-ascending deterministic:
// wave w's start = offsets[e] + sum of stripe-counts of waves < w.
__global__ __launch_bounds__(512) void build_lists8_kernel(
    const int2* __restrict__ tk_idx, const float2* __restrict__ tk_w,
    int* __restrict__ counts, int* __restrict__ offsets,
    int* __restrict__ tok_list, float* __restrict__ wt_list,
    float* __restrict__ cnt_out) {
  __shared__ int s_cnt[8][NE];           // [wave][expert]
  const int e = blockIdx.x;
  const int w = threadIdx.x >> 6, lane = threadIdx.x & 63;
  const int tbase = w * 512;
  int cnt[NE];
  #pragma unroll
  for (int ee = 0; ee < NE; ee++) cnt[ee] = 0;
  #pragma unroll
  for (int it = 0; it < 8; it++) {
    int2 idx = tk_idx[tbase + it * 64 + lane];
    #pragma unroll
    for (int ee = 0; ee < NE; ee++)
      cnt[ee] += __popcll(__ballot(idx.x == ee || idx.y == ee));
  }
  if (lane == 0) {
    #pragma unroll
    for (int ee = 0; ee < NE; ee++) s_cnt[w][ee] = cnt[ee];
  }
  __syncthreads();
  int total[NE];
  #pragma unroll
  for (int ee = 0; ee < NE; ee++) {
    int s = 0;
    #pragma unroll
    for (int ww = 0; ww < 8; ww++) s += s_cnt[ww][ee];
    total[ee] = s;
  }
  int off = 0;
  for (int ee = 0; ee < e; ee++) off += total[ee];
  if (threadIdx.x == 0) {
    counts[e]  = total[e];
    offsets[e] = off;
    cnt_out[e] = (float)total[e];
  }
  int pos = off;
  for (int ww = 0; ww < w; ww++) pos += s_cnt[ww][e];
  // emit this wave's stripe for expert e
  #pragma unroll
  for (int it = 0; it < 8; it++) {
    int tok = tbase + it * 64 + lane;
    int2 idx = tk_idx[tok];
    float2 wt = tk_w[tok];
    bool m0 = (idx.x == e), m1 = (idx.y == e);
    bool m = m0 || m1;
    unsigned long long mask = __ballot(m);
    if (m) {
      int p = pos + __popcll(mask & ((1ull << lane) - 1ull));
      tok_list[p] = tok;
      wt_list[p]  = m0 ? wt.x : wt.y;
    }
    pos += __popcll(mask);
  }
}

// ---------------- gather + convert: xg[slot][:] = bf16(x[tok_list[slot]][:]) ----------------
__global__ __launch_bounds__(256) void gather_x_kernel(const float* __restrict__ x,
                                                       const int* __restrict__ tok_list,
                                                       u16* __restrict__ xg) {
  int g = blockIdx.x;
  int tok = tok_list[g];
  int c = threadIdx.x * 4;
  float4 v = *(const float4*)(x + (size_t)tok * DIM + c);
  ushort4 o;
  o.x = f2bf(v.x); o.y = f2bf(v.y); o.z = f2bf(v.z); o.w = f2bf(v.w);
  *(ushort4*)(xg + (size_t)g * DIM + c) = o;
}

// ---------------- MoE GEMM v2 (round-1 verbatim): 2-phase prefetch, BK=64, 8 waves, T2 swizzle ----
// MODE 0: xg[slot][DIM] x w1t[e][FF][DIM] -> h (gelu, bf16)
// MODE 1: h[slot][FF]   x w2t[e][DIM][FF] -> out (scaled atomic f32)
template <int MODE, int BM, int BN>
__global__ __launch_bounds__(512, 2) void moe_gemm2_kernel(
    const u16* __restrict__ Abase, const u16* __restrict__ Bbase,
    const float* __restrict__ bias,
    const int* __restrict__ counts, const int* __restrict__ offsets,
    const int* __restrict__ tok_list, const float* __restrict__ wt_list,
    u16* __restrict__ Hout, float* __restrict__ Out) {
  constexpr int KT = (MODE == 0) ? DIM : FF;   // reduction length
  constexpr int NT = (MODE == 0) ? FF : DIM;   // output width
  constexpr int LA = BM / 64;                  // A gloads / thread / K-tile
  constexpr int LB = BN / 64;                  // B gloads / thread / K-tile
  constexpr int MR = BM / 32;                  // M frags per wave (2 M-waves)
  constexpr int NR = BN / 64;                  // N frags per wave (4 N-waves)
  constexpr int ASZ = BM * 64;                 // u16 per A buffer
  constexpr int BSZ = BN * 64;
  constexpr int NTILES = KT / 64;

  extern __shared__ u16 sm[];                  // [2*ASZ + 2*BSZ]

  const int e  = blockIdx.z;
  const int ne = counts[e];
  const int m0 = blockIdx.y * BM;
  if (m0 >= ne) return;
  const int n0   = blockIdx.x * BN;
  const int offs = offsets[e];

  const int t = threadIdx.x;
  const int wave = t >> 6, lane = t & 63;
  const int quad = lane >> 4, l16 = lane & 15;
  const int wmb = (wave & 1) * (BM / 2);
  const int wnb = (wave >> 1) * (BN / 4);

  // ---- staging pointers (global source pre-swizzled; LDS dest linear in thread id) ----
  const u16* aptr[LA];
  const u16* bptr[LB];
  #pragma unroll
  for (int p = 0; p < LA; p++) {
    int idx = p * 512 + t;
    int row = idx >> 3, c = idx & 7;
    int clog = c ^ (row & 7);
    int s = m0 + row; if (s > ne - 1) s = ne - 1;   // clamped gather (dup last row)
    aptr[p] = Abase + (size_t)(offs + s) * KT + clog * 8;
  }
  #pragma unroll
  for (int p = 0; p < LB; p++) {
    int idx = p * 512 + t;
    int row = idx >> 3, c = idx & 7;
    int clog = c ^ (row & 7);
    bptr[p] = Bbase + ((size_t)e * NT + n0 + row) * KT + clog * 8;
  }

  auto stage = [&](int buf, int k0) {
    #pragma unroll
    for (int p = 0; p < LA; p++)
      gload_lds16(aptr[p] + k0, sm + buf * ASZ + (p * 512 + t) * 8);
    #pragma unroll
    for (int p = 0; p < LB; p++)
      gload_lds16(bptr[p] + k0, sm + 2 * ASZ + buf * BSZ + (p * 512 + t) * 8);
  };

  // ---- loop-invariant fragment read offsets (u16 units) ----
  const int xrow = l16 & 7;
  const int xo[2] = { ((0 + quad) ^ xrow) * 8, ((4 + quad) ^ xrow) * 8 };
  const int abase0 = (wmb + l16) * 64;              // + i*1024 + xo[kk]
  const int bbase0 = 2 * ASZ + (wnb + l16) * 64;    // + j*1024 + xo[kk]

  f32x4 acc[MR][NR];
  #pragma unroll
  for (int i = 0; i < MR; i++)
    #pragma unroll
    for (int j = 0; j < NR; j++)
      acc[i][j] = (f32x4){0.f, 0.f, 0.f, 0.f};

  // ---- 2-phase main loop: issue next-tile stage, compute current, ONE vmcnt(0)+barrier ----
  stage(0, 0);
  __syncthreads();
  int cur = 0;
  for (int kt = 0; kt < NTILES; ++kt) {
    if (kt + 1 < NTILES) stage(cur ^ 1, (kt + 1) * 64);
    const u16* As = sm + cur * ASZ;
    const u16* Bs = sm + cur * BSZ;   // bbase0 already includes the 2*ASZ offset
    #pragma unroll
    for (int kk = 0; kk < 2; kk++) {
      bf16x8 a[MR], b[NR];
      #pragma unroll
      for (int i = 0; i < MR; i++) a[i] = *(const bf16x8*)&As[abase0 + i * 1024 + xo[kk]];
      #pragma unroll
      for (int j = 0; j < NR; j++) b[j] = *(const bf16x8*)&Bs[bbase0 + j * 1024 + xo[kk]];
      #pragma unroll
      for (int i = 0; i < MR; i++)
        #pragma unroll
        for (int j = 0; j < NR; j++)
          acc[i][j] = __builtin_amdgcn_mfma_f32_16x16x32_bf16(a[i], b[j], acc[i][j], 0, 0, 0);
    }
    __syncthreads();   // drains vmcnt(0) (next-tile stage) + lgkmcnt; then barrier
    cur ^= 1;
  }

  // ---- epilogue ----
  if (MODE == 0) {
    const float* bb = bias + (size_t)e * FF + n0 + wnb;
    float bc[NR];
    #pragma unroll
    for (int j = 0; j < NR; j++) bc[j] = bb[j * 16 + l16];
    #pragma unroll
    for (int i = 0; i < MR; i++) {
      #pragma unroll
      for (int r = 0; r < 4; r++) {
        int s = m0 + wmb + i * 16 + quad * 4 + r;
        if (s < ne) {
          u16* hr = Hout + (size_t)(offs + s) * FF + n0 + wnb;
          #pragma unroll
          for (int j = 0; j < NR; j++)
            hr[j * 16 + l16] = f2bf(gelu_f(acc[i][j][r] + bc[j]));
        }
      }
    }
  } else {
    const float* bb = bias + (size_t)e * DIM + n0 + wnb;
    float bc[NR];
    #pragma unroll
    for (int j = 0; j < NR; j++) bc[j] = bb[j * 16 + l16];
    #pragma unroll
    for (int i = 0; i < MR; i++) {
      #pragma unroll
      for (int r = 0; r < 4; r++) {
        int s = m0 + wmb + i * 16 + quad * 4 + r;
        if (s < ne) {
          int   tok = tok_list[offs + s];
          float w   = wt_list[offs + s];
          float* orow = Out + (size_t)tok * DIM + n0 + wnb;
          #pragma unroll
          for (int j = 0; j < NR; j++)
            atomicAdd(&orow[j * 16 + l16], (acc[i][j][r] + bc[j]) * w);
        }
      }
    }
  }
}

extern "C" void kernel_launch(void* const* d_in, const int* in_sizes, int n_in,
                              void* d_out, int out_size, void* d_ws, size_t ws_size,
                              hipStream_t stream) {
  const float* x   = (const float*)d_in[0];
  const float* gw  = (const float*)d_in[1];
  const float* gb  = (const float*)d_in[2];
  const float* w1  = (const float*)d_in[3];
  const float* b1  = (const float*)d_in[4];
  const float* w2  = (const float*)d_in[5];
  const float* b2  = (const float*)d_in[6];
  float* out = (float*)d_out;
  char*  ws  = (char*)d_ws;

  // ws layout
  u16* w1t = (u16*)(ws);                                    // 64 MB  [E][FF][DIM]
  u16* w2t = (u16*)(ws + 1ull * 67108864);                  // 64 MB  [E][DIM][FF]
  u16* h   = (u16*)(ws + 2ull * 67108864);                  // 64 MB  [8192][FF]
  u16* xg  = (u16*)(ws + 3ull * 67108864);                  // 16 MB  [8192][DIM]
  char* meta = ws + 3ull * 67108864 + 16777216;
  int*    counts   = (int*)(meta);
  int*    offsets  = (int*)(meta + 64);
  int*    tok_list = (int*)(meta + 128);                    // flat [8192]
  float*  wt_list  = (float*)(meta + 128 + 32768);          // flat [8192]
  int2*   tk_idx   = (int2*)(meta + 128 + 2 * 32768);       // [4096]
  float2* tk_w     = (float2*)(meta + 128 + 2 * 32768 + 32768);
  (void)in_sizes; (void)n_in; (void)out_size; (void)ws_size;

  // dynamic-LDS opt-in (>64KB); host-side, not a stream op (graph-capture safe)
  static bool attr_set = false;
  if (!attr_set) {
    hipFuncSetAttribute(reinterpret_cast<const void*>(moe_gemm2_kernel<0, 256, 256>),
                        hipFuncAttributeMaxDynamicSharedMemorySize, 131072);
    hipFuncSetAttribute(reinterpret_cast<const void*>(moe_gemm2_kernel<1, 128, 256>),
                        hipFuncAttributeMaxDynamicSharedMemorySize, 98304);
    attr_set = true;
  }

  hipMemsetAsync(out, 0, (size_t)OUT_LOGITS * 4, stream);   // zero main output (atomics accumulate)

  transpose_cvt3_kernel<<<8192, 256, 0, stream>>>(w1, w1t, w2, w2t);
  gate_kernel<<<NTOK / 4, 256, 0, stream>>>(x, gw, gb, out, tk_idx, tk_w);
  build_lists8_kernel<<<NE, 512, 0, stream>>>(tk_idx, tk_w, counts, offsets, tok_list, wt_list,
                                              out + OUT_CNT);
  gather_x_kernel<<<2 * NTOK, 256, 0, stream>>>(x, tok_list, xg);

  // GEMM1: M=slots(~8192 over experts), N=4096, K=1024 -> 256x256 tiles
  moe_gemm2_kernel<0, 256, 256><<<dim3(FF / 256, NTOK / 256, NE), 512, 131072, stream>>>(
      xg, w1t, b1, counts, offsets, tok_list, wt_list, h, nullptr);
  // GEMM2: M=slots, N=1024, K=4096 -> 128x256 tiles
  moe_gemm2_kernel<1, 128, 256><<<dim3(DIM / 256, NTOK / 128, NE), 512, 98304, stream>>>(
      h, w2t, b2, counts, offsets, tok_list, wt_list, nullptr, out);
}